// Round 4
// baseline (1407.699 us; speedup 1.0000x reference)
//
#include <hip/hip_runtime.h>

typedef unsigned short u16;
typedef __bf16 bf16x8 __attribute__((ext_vector_type(8)));
typedef float floatx4 __attribute__((ext_vector_type(4)));

__device__ __forceinline__ float u2f(u16 u) { return __uint_as_float(((unsigned)u) << 16); }
__device__ __forceinline__ u16 f2u(float f) {
    unsigned x = __float_as_uint(f);
    x += 0x7fffu + ((x >> 16) & 1u);   // RNE to bf16
    return (u16)(x >> 16);
}

// ---------------- prep kernels ----------------
__global__ void k_fill_f32(float* p, float v, int n) {
    int i = blockIdx.x * blockDim.x + threadIdx.x;
    if (i < n) p[i] = v;
}
__global__ void k_fill_i32(int* p, int v, int n) {
    int i = blockIdx.x * blockDim.x + threadIdx.x;
    if (i < n) p[i] = v;
}
__global__ void k_deg_accum(const int* __restrict__ dst, const float* __restrict__ ew,
                            float* __restrict__ deg, int E) {
    int e = blockIdx.x * blockDim.x + threadIdx.x;
    if (e < E) atomicAdd(&deg[dst[e]], ew[e]);
}
__global__ void k_finish_deg(const float* __restrict__ deg, float* __restrict__ dinv,
                             float* __restrict__ dinv2, int n) {
    int i = blockIdx.x * blockDim.x + threadIdx.x;
    if (i < n) { float r = rsqrtf(deg[i]); dinv[i] = r; dinv2[i] = r * r; }
}
__global__ void k_count(const int* __restrict__ dst, int* __restrict__ cnt, int E) {
    int e = blockIdx.x * blockDim.x + threadIdx.x;
    if (e < E) atomicAdd(&cnt[dst[e]], 1);
}
// single-block exclusive scan over n=16384 counts -> off[0..n]
__global__ void k_scan(const int* __restrict__ cnt, int* __restrict__ off, int n) {
    __shared__ int sh[1024];
    int t = threadIdx.x;
    const int per = n / 1024;   // 16
    int base = t * per;
    int loc[16];
    int s = 0;
    for (int j = 0; j < per; ++j) { loc[j] = s; s += cnt[base + j]; }
    sh[t] = s;
    __syncthreads();
    for (int d = 1; d < 1024; d <<= 1) {
        int v = (t >= d) ? sh[t - d] : 0;
        __syncthreads();
        sh[t] += v;
        __syncthreads();
    }
    int prev = (t == 0) ? 0 : sh[t - 1];
    for (int j = 0; j < per; ++j) off[base + j] = prev + loc[j];
    if (t == 1023) off[n] = prev + s;
}
__global__ void k_fill_csr(const int* __restrict__ src, const int* __restrict__ dst,
                           const float* __restrict__ ew, const float* __restrict__ dinv,
                           const int* __restrict__ off, int* __restrict__ cur,
                           int* __restrict__ csr_src, float* __restrict__ csr_w, int E) {
    int e = blockIdx.x * blockDim.x + threadIdx.x;
    if (e < E) {
        int d = dst[e], s = src[e];
        int p = off[d] + atomicAdd(&cur[d], 1);
        csr_src[p] = s;
        csr_w[p] = dinv[s] * ew[e] * dinv[d];
    }
}
// W[K][M] (f32) -> Wt[Mpad][K] (bf16), zero-filled for m >= M. grid(Mpad/32, K/32), block(32,8)
__global__ void k_transpose(const float* __restrict__ W, u16* __restrict__ Wt, int K, int M) {
    __shared__ u16 tile[32][33];
    int m0 = blockIdx.x * 32, k0 = blockIdx.y * 32;
    int tx = threadIdx.x, ty = threadIdx.y;
    #pragma unroll
    for (int rr = 0; rr < 4; ++rr) {
        int r = ty + rr * 8;
        int m = m0 + tx, k = k0 + r;
        tile[r][tx] = (m < M) ? f2u(W[(size_t)k * M + m]) : (u16)0;
    }
    __syncthreads();
    #pragma unroll
    for (int rr = 0; rr < 4; ++rr) {
        int r = ty + rr * 8;
        Wt[(size_t)(m0 + r) * K + k0 + tx] = tile[tx][r];
    }
}

// ---------------- GEMM: C[16384 x Nreal] = A[16384 x K] * Bt[Npad x K]^T ----------------
// 128x128 tile, BK=32, 4 waves in 2x2, each wave 4x4 of 16x16x32 MFMA.
// A, Bt are bf16 (u16). C is CT (u16 -> bf16 store, float -> f32 store). bias is f32.
// LDS layout: As[row*32 + k] (u16); 16B chunk c holds row c>>2, k in [(c&3)*8, +8).
// EPI: 0 = none, 1 = +bias, 2 = relu(+bias)
template <int EPI, typename CT>
__global__ __launch_bounds__(256)
void gemm_bt(const u16* __restrict__ A, const u16* __restrict__ Bt,
             const float* __restrict__ bias, CT* __restrict__ C,
             int K, int Nreal, int ldc) {
    __shared__ u16 As[128 * 32];
    __shared__ u16 Bs[128 * 32];
    const int t = threadIdx.x;
    const int lane = t & 63;
    const int wave = t >> 6;
    const int waveM = wave >> 1, waveN = wave & 1;
    const int quad = lane >> 4, l16 = lane & 15;
    const size_t row0 = (size_t)blockIdx.x * 128;
    const size_t col0 = (size_t)blockIdx.y * 128;

    floatx4 acc[4][4];
    #pragma unroll
    for (int i = 0; i < 4; ++i)
        #pragma unroll
        for (int j = 0; j < 4; ++j) acc[i][j] = (floatx4){0.f, 0.f, 0.f, 0.f};

    // thread t stages 16B chunks t and 256+t of each of As/Bs:
    //   chunk c: row = c>>2, k-elems [(c&3)*8, +8)
    const int r0 = t >> 2;            // rows 0..63
    const int r1 = 64 + (t >> 2);     // rows 64..127
    const int kc = (t & 3) * 8;
    const u16* Abase = A + row0 * K;
    const u16* Bbase = Bt + col0 * K;

    for (int k0 = 0; k0 < K; k0 += 32) {
        uint4 ga0 = *(const uint4*)(Abase + (size_t)r0 * K + k0 + kc);
        uint4 ga1 = *(const uint4*)(Abase + (size_t)r1 * K + k0 + kc);
        uint4 gb0 = *(const uint4*)(Bbase + (size_t)r0 * K + k0 + kc);
        uint4 gb1 = *(const uint4*)(Bbase + (size_t)r1 * K + k0 + kc);
        __syncthreads();   // prior iteration's ds_reads complete before overwrite
        *(uint4*)((char*)As + (size_t)t * 16)         = ga0;
        *(uint4*)((char*)As + (size_t)(256 + t) * 16) = ga1;
        *(uint4*)((char*)Bs + (size_t)t * 16)         = gb0;
        *(uint4*)((char*)Bs + (size_t)(256 + t) * 16) = gb1;
        __syncthreads();
        bf16x8 af[4], bfv[4];
        #pragma unroll
        for (int mi = 0; mi < 4; ++mi)
            af[mi] = *(const bf16x8*)&As[(waveM * 64 + mi * 16 + l16) * 32 + quad * 8];
        #pragma unroll
        for (int ni = 0; ni < 4; ++ni)
            bfv[ni] = *(const bf16x8*)&Bs[(waveN * 64 + ni * 16 + l16) * 32 + quad * 8];
        #pragma unroll
        for (int mi = 0; mi < 4; ++mi)
            #pragma unroll
            for (int ni = 0; ni < 4; ++ni)
                acc[mi][ni] = __builtin_amdgcn_mfma_f32_16x16x32_bf16(af[mi], bfv[ni],
                                                                      acc[mi][ni], 0, 0, 0);
    }

    // C/D layout (m89-verified): col = lane&15, row = quad*4 + r
    #pragma unroll
    for (int ni = 0; ni < 4; ++ni) {
        const int col = (int)col0 + waveN * 64 + ni * 16 + l16;
        if (col >= Nreal) continue;
        const float bv = (EPI != 0) ? bias[col] : 0.f;
        #pragma unroll
        for (int mi = 0; mi < 4; ++mi) {
            #pragma unroll
            for (int r = 0; r < 4; ++r) {
                size_t row = row0 + waveM * 64 + mi * 16 + quad * 4 + r;
                float v = acc[mi][ni][r] + bv;
                if (EPI == 2) v = fmaxf(v, 0.f);
                if constexpr (sizeof(CT) == 2) C[row * (size_t)ldc + col] = (CT)f2u(v);
                else                           C[row * (size_t)ldc + col] = (CT)v;
            }
        }
    }
}

// 8-wide row load -> f32, for f32 or bf16 source
__device__ __forceinline__ void load8_f(const float* p, float* v) {
    float4 a = *(const float4*)p;
    float4 b = *(const float4*)(p + 4);
    v[0] = a.x; v[1] = a.y; v[2] = a.z; v[3] = a.w;
    v[4] = b.x; v[5] = b.y; v[6] = b.z; v[7] = b.w;
}
__device__ __forceinline__ void load8_b(const u16* p, float* v) {
    uint4 a = *(const uint4*)p;
    const u16* ap = (const u16*)&a;
    #pragma unroll
    for (int j = 0; j < 8; ++j) v[j] = u2f(ap[j]);
}

// ---------- aggregation (pre-GEMM): Xa[i] = dinv2[i]*X[i] + sum_e w_e * X[src_e]; Xa bf16 ----------
template <typename XT>
__global__ __launch_bounds__(128)
void k_agg_pre(const XT* __restrict__ X, const int* __restrict__ off,
               const int* __restrict__ csr_src, const float* __restrict__ csr_w,
               const float* __restrict__ dinv2, u16* __restrict__ Xa, int F) {
    const int i = blockIdx.x;
    const int e0 = off[i], e1 = off[i + 1];
    const float d2 = dinv2[i];
    for (int f = threadIdx.x * 8; f < F; f += 128 * 8) {
        float acc[8], hv[8];
        if constexpr (sizeof(XT) == 2) load8_b((const u16*)&X[(size_t)i * F + f], hv);
        else                           load8_f((const float*)&X[(size_t)i * F + f], hv);
        #pragma unroll
        for (int j = 0; j < 8; ++j) acc[j] = d2 * hv[j];
        for (int e = e0; e < e1; ++e) {
            int s = csr_src[e];
            float w = csr_w[e];
            float sv[8];
            if constexpr (sizeof(XT) == 2) load8_b((const u16*)&X[(size_t)s * F + f], sv);
            else                           load8_f((const float*)&X[(size_t)s * F + f], sv);
            #pragma unroll
            for (int j = 0; j < 8; ++j) acc[j] = fmaf(w, sv[j], acc[j]);
        }
        uint4 ov;
        u16* op = (u16*)&ov;
        #pragma unroll
        for (int j = 0; j < 8; ++j) op[j] = f2u(acc[j]);
        *(uint4*)&Xa[(size_t)i * F + f] = ov;
    }
}

// ---------- aggregation (post-GEMM): X[i] = relu(b + dinv2[i]*H[i] + sum_e w_e*H[src_e]) ----------
__global__ __launch_bounds__(128)
void k_agg_post(const u16* __restrict__ H, const int* __restrict__ off,
                const int* __restrict__ csr_src, const float* __restrict__ csr_w,
                const float* __restrict__ dinv2, const float* __restrict__ bias,
                u16* __restrict__ X, int F) {
    const int i = blockIdx.x;
    const int e0 = off[i], e1 = off[i + 1];
    const float d2 = dinv2[i];
    for (int f = threadIdx.x * 8; f < F; f += 128 * 8) {
        float acc[8], hv[8];
        load8_b(&H[(size_t)i * F + f], hv);
        #pragma unroll
        for (int j = 0; j < 8; ++j) acc[j] = fmaf(d2, hv[j], bias[f + j]);
        for (int e = e0; e < e1; ++e) {
            int s = csr_src[e];
            float w = csr_w[e];
            float sv[8];
            load8_b(&H[(size_t)s * F + f], sv);
            #pragma unroll
            for (int j = 0; j < 8; ++j) acc[j] = fmaf(w, sv[j], acc[j]);
        }
        uint4 ov;
        u16* op = (u16*)&ov;
        #pragma unroll
        for (int j = 0; j < 8; ++j) op[j] = f2u(fmaxf(acc[j], 0.f));
        *(uint4*)&X[(size_t)i * F + f] = ov;
    }
}

// ---------------- launch ----------------
extern "C" void kernel_launch(void* const* d_in, const int* in_sizes, int n_in,
                              void* d_out, int out_size, void* d_ws, size_t ws_size,
                              hipStream_t stream) {
    const int N = 16384, E = 65536;
    const float* x   = (const float*)d_in[0];
    const int*   src = (const int*)d_in[1];
    const int*   dst = (const int*)d_in[2];
    const float* ew  = (const float*)d_in[3];
    const float* W[5] = {(const float*)d_in[4], (const float*)d_in[6], (const float*)d_in[8],
                         (const float*)d_in[10], (const float*)d_in[12]};
    const float* b[5] = {(const float*)d_in[5], (const float*)d_in[7], (const float*)d_in[9],
                         (const float*)d_in[11], (const float*)d_in[13]};
    static const int Kd[5] = {512, 1024, 2048, 4096, 2048};   // GEMM K per layer
    static const int Md[5] = {1024, 2048, 4096, 2048, 1000};  // real out cols
    static const int Mp[5] = {1024, 2048, 4096, 2048, 1024};  // padded out cols

    char* ws = (char*)d_ws;
    size_t o = 0;
    auto alloc = [&](size_t bytes) -> void* {
        void* p = ws + o;
        o = (o + bytes + 255) & ~(size_t)255;
        return p;
    };
    // ping-pong activations (bf16): P up to 4096-wide, Q up to 2048-wide  (~234 MiB total ws)
    u16* P = (u16*)alloc((size_t)N * 4096 * 2);   // 128 MiB
    u16* Q = (u16*)alloc((size_t)N * 2048 * 2);   //  64 MiB
    u16* Wt[5];
    for (int i = 0; i < 5; ++i) Wt[i] = (u16*)alloc((size_t)Mp[i] * Kd[i] * 2);  // ~41 MB
    float* deg   = (float*)alloc(N * 4);
    float* dinv  = (float*)alloc(N * 4);
    float* dinv2 = (float*)alloc(N * 4);
    int* cnt     = (int*)alloc(N * 4);
    int* cur     = (int*)alloc(N * 4);
    int* off     = (int*)alloc((N + 1) * 4);
    int* csr_src = (int*)alloc(E * 4);
    float* csr_w = (float*)alloc(E * 4);
    (void)ws_size; (void)in_sizes; (void)n_in; (void)out_size;

    // graph prep
    k_fill_f32<<<N / 256, 256, 0, stream>>>(deg, 1.0f, N);
    k_fill_i32<<<N / 256, 256, 0, stream>>>(cnt, 0, N);
    k_fill_i32<<<N / 256, 256, 0, stream>>>(cur, 0, N);
    k_deg_accum<<<E / 256, 256, 0, stream>>>(dst, ew, deg, E);
    k_finish_deg<<<N / 256, 256, 0, stream>>>(deg, dinv, dinv2, N);
    k_count<<<E / 256, 256, 0, stream>>>(dst, cnt, E);
    k_scan<<<1, 1024, 0, stream>>>(cnt, off, N);
    k_fill_csr<<<E / 256, 256, 0, stream>>>(src, dst, ew, dinv, off, cur, csr_src, csr_w, E);

    // weight transposes f32 -> bf16 (pad Wout cols 1000 -> 1024 with zeros)
    for (int i = 0; i < 5; ++i)
        k_transpose<<<dim3(Mp[i] / 32, Kd[i] / 32), dim3(32, 8), 0, stream>>>(W[i], Wt[i], Kd[i], Md[i]);

    // L1..L3: agg-first (A-hat linear => agg(X W) = (agg X) W), bias+relu in GEMM epilogue
    k_agg_pre<float><<<N, 128, 0, stream>>>(x, off, csr_src, csr_w, dinv2, Q, 512);
    gemm_bt<2, u16><<<dim3(128, Mp[0] / 128), 256, 0, stream>>>(Q, Wt[0], b[0], P, Kd[0], Md[0], Md[0]);
    k_agg_pre<u16><<<N, 128, 0, stream>>>(P, off, csr_src, csr_w, dinv2, Q, 1024);
    gemm_bt<2, u16><<<dim3(128, Mp[1] / 128), 256, 0, stream>>>(Q, Wt[1], b[1], P, Kd[1], Md[1], Md[1]);
    k_agg_pre<u16><<<N, 128, 0, stream>>>(P, off, csr_src, csr_w, dinv2, Q, 2048);
    gemm_bt<2, u16><<<dim3(128, Mp[2] / 128), 256, 0, stream>>>(Q, Wt[2], b[2], P, Kd[2], Md[2], Md[2]);
    // L4: GEMM-then-agg (agg at 2048 instead of 4096)
    gemm_bt<0, u16><<<dim3(128, Mp[3] / 128), 256, 0, stream>>>(P, Wt[3], nullptr, Q, Kd[3], Md[3], Md[3]);
    k_agg_post<<<N, 128, 0, stream>>>(Q, off, csr_src, csr_w, dinv2, b[3], P, 2048);
    // L5: output projection -> d_out f32 (Nreal=1000, ldc=1000)
    gemm_bt<1, float><<<dim3(128, Mp[4] / 128), 256, 0, stream>>>(P, Wt[4], b[4], (float*)d_out, Kd[4], Md[4], 1000);
}

// Round 5
// 1353.843 us; speedup vs baseline: 1.0398x; 1.0398x over previous
//
#include <hip/hip_runtime.h>

typedef unsigned short u16;
typedef __bf16 bf16x8 __attribute__((ext_vector_type(8)));
typedef float floatx4 __attribute__((ext_vector_type(4)));

__device__ __forceinline__ float u2f(u16 u) { return __uint_as_float(((unsigned)u) << 16); }
__device__ __forceinline__ u16 f2u(float f) {
    unsigned x = __float_as_uint(f);
    x += 0x7fffu + ((x >> 16) & 1u);   // RNE to bf16
    return (u16)(x >> 16);
}

// ---------------- prep kernels ----------------
__global__ void k_fill_f32(float* p, float v, int n) {
    int i = blockIdx.x * blockDim.x + threadIdx.x;
    if (i < n) p[i] = v;
}
__global__ void k_fill_i32(int* p, int v, int n) {
    int i = blockIdx.x * blockDim.x + threadIdx.x;
    if (i < n) p[i] = v;
}
__global__ void k_deg_accum(const int* __restrict__ dst, const float* __restrict__ ew,
                            float* __restrict__ deg, int E) {
    int e = blockIdx.x * blockDim.x + threadIdx.x;
    if (e < E) atomicAdd(&deg[dst[e]], ew[e]);
}
__global__ void k_finish_deg(const float* __restrict__ deg, float* __restrict__ dinv,
                             float* __restrict__ dinv2, int n) {
    int i = blockIdx.x * blockDim.x + threadIdx.x;
    if (i < n) { float r = rsqrtf(deg[i]); dinv[i] = r; dinv2[i] = r * r; }
}
__global__ void k_count(const int* __restrict__ dst, int* __restrict__ cnt, int E) {
    int e = blockIdx.x * blockDim.x + threadIdx.x;
    if (e < E) atomicAdd(&cnt[dst[e]], 1);
}
// single-block exclusive scan over n=16384 counts -> off[0..n]
__global__ void k_scan(const int* __restrict__ cnt, int* __restrict__ off, int n) {
    __shared__ int sh[1024];
    int t = threadIdx.x;
    const int per = n / 1024;   // 16
    int base = t * per;
    int loc[16];
    int s = 0;
    for (int j = 0; j < per; ++j) { loc[j] = s; s += cnt[base + j]; }
    sh[t] = s;
    __syncthreads();
    for (int d = 1; d < 1024; d <<= 1) {
        int v = (t >= d) ? sh[t - d] : 0;
        __syncthreads();
        sh[t] += v;
        __syncthreads();
    }
    int prev = (t == 0) ? 0 : sh[t - 1];
    for (int j = 0; j < per; ++j) off[base + j] = prev + loc[j];
    if (t == 1023) off[n] = prev + s;
}
__global__ void k_fill_csr(const int* __restrict__ src, const int* __restrict__ dst,
                           const float* __restrict__ ew, const float* __restrict__ dinv,
                           const int* __restrict__ off, int* __restrict__ cur,
                           int* __restrict__ csr_src, float* __restrict__ csr_w, int E) {
    int e = blockIdx.x * blockDim.x + threadIdx.x;
    if (e < E) {
        int d = dst[e], s = src[e];
        int p = off[d] + atomicAdd(&cur[d], 1);
        csr_src[p] = s;
        csr_w[p] = dinv[s] * ew[e] * dinv[d];
    }
}
// W[K][M] (f32) -> Wt[Mpad][K] (bf16), zero-filled for m >= M. grid(Mpad/32, K/32), block(32,8)
__global__ void k_transpose(const float* __restrict__ W, u16* __restrict__ Wt, int K, int M) {
    __shared__ u16 tile[32][33];
    int m0 = blockIdx.x * 32, k0 = blockIdx.y * 32;
    int tx = threadIdx.x, ty = threadIdx.y;
    #pragma unroll
    for (int rr = 0; rr < 4; ++rr) {
        int r = ty + rr * 8;
        int m = m0 + tx, k = k0 + r;
        tile[r][tx] = (m < M) ? f2u(W[(size_t)k * M + m]) : (u16)0;
    }
    __syncthreads();
    #pragma unroll
    for (int rr = 0; rr < 4; ++rr) {
        int r = ty + rr * 8;
        Wt[(size_t)(m0 + r) * K + k0 + tx] = tile[tx][r];
    }
}

// ---------------- GEMM: C[16384 x Nreal] = A[16384 x K] * Bt[Npad x K]^T ----------------
// 128x128 tile, BK=32, 4 waves in 2x2, each wave 4x4 of 16x16x32 MFMA.
// Register-prefetch double buffer: global loads for tile k+1 issue before MFMA of tile k,
// so the vmcnt wait (at next iter's LDS store) is covered by MFMA + ds_reads.
// Grid: x = col tile (fastest -> consecutive blocks share the A row-panel), y = row tile.
// EPI: 0 = none, 1 = +bias, 2 = relu(+bias)
template <int EPI, typename CT>
__global__ __launch_bounds__(256)
void gemm_bt(const u16* __restrict__ A, const u16* __restrict__ Bt,
             const float* __restrict__ bias, CT* __restrict__ C,
             int K, int Nreal, int ldc) {
    __shared__ u16 As[128 * 32];
    __shared__ u16 Bs[128 * 32];
    const int t = threadIdx.x;
    const int lane = t & 63;
    const int wave = t >> 6;
    const int waveM = wave >> 1, waveN = wave & 1;
    const int quad = lane >> 4, l16 = lane & 15;
    const size_t row0 = (size_t)blockIdx.y * 128;
    const size_t col0 = (size_t)blockIdx.x * 128;

    floatx4 acc[4][4];
    #pragma unroll
    for (int i = 0; i < 4; ++i)
        #pragma unroll
        for (int j = 0; j < 4; ++j) acc[i][j] = (floatx4){0.f, 0.f, 0.f, 0.f};

    // thread t stages 16B chunks t and 256+t of each of As/Bs:
    //   chunk c: row = c>>2, k-elems [(c&3)*8, +8)
    const int r0 = t >> 2;            // rows 0..63
    const int r1 = 64 + (t >> 2);     // rows 64..127
    const int kc = (t & 3) * 8;
    const u16* Abase = A + row0 * K;
    const u16* Bbase = Bt + col0 * K;

    uint4 ga0, ga1, gb0, gb1;
    {
        ga0 = *(const uint4*)(Abase + (size_t)r0 * K + kc);
        ga1 = *(const uint4*)(Abase + (size_t)r1 * K + kc);
        gb0 = *(const uint4*)(Bbase + (size_t)r0 * K + kc);
        gb1 = *(const uint4*)(Bbase + (size_t)r1 * K + kc);
    }

    for (int k0 = 0; k0 < K; k0 += 32) {
        __syncthreads();   // prior iteration's ds_reads complete before overwrite
        *(uint4*)((char*)As + (size_t)t * 16)         = ga0;
        *(uint4*)((char*)As + (size_t)(256 + t) * 16) = ga1;
        *(uint4*)((char*)Bs + (size_t)t * 16)         = gb0;
        *(uint4*)((char*)Bs + (size_t)(256 + t) * 16) = gb1;
        __syncthreads();
        // prefetch next K-tile into registers (in flight during MFMA below)
        const int kn = (k0 + 32 < K) ? (k0 + 32) : 0;   // wave-uniform; dummy re-read on last iter
        ga0 = *(const uint4*)(Abase + (size_t)r0 * K + kn + kc);
        ga1 = *(const uint4*)(Abase + (size_t)r1 * K + kn + kc);
        gb0 = *(const uint4*)(Bbase + (size_t)r0 * K + kn + kc);
        gb1 = *(const uint4*)(Bbase + (size_t)r1 * K + kn + kc);

        bf16x8 af[4], bfv[4];
        #pragma unroll
        for (int mi = 0; mi < 4; ++mi)
            af[mi] = *(const bf16x8*)&As[(waveM * 64 + mi * 16 + l16) * 32 + quad * 8];
        #pragma unroll
        for (int ni = 0; ni < 4; ++ni)
            bfv[ni] = *(const bf16x8*)&Bs[(waveN * 64 + ni * 16 + l16) * 32 + quad * 8];
        #pragma unroll
        for (int mi = 0; mi < 4; ++mi)
            #pragma unroll
            for (int ni = 0; ni < 4; ++ni)
                acc[mi][ni] = __builtin_amdgcn_mfma_f32_16x16x32_bf16(af[mi], bfv[ni],
                                                                      acc[mi][ni], 0, 0, 0);
    }

    // C/D layout (m89-verified): col = lane&15, row = quad*4 + r
    #pragma unroll
    for (int ni = 0; ni < 4; ++ni) {
        const int col = (int)col0 + waveN * 64 + ni * 16 + l16;
        if (col >= Nreal) continue;
        const float bv = (EPI != 0) ? bias[col] : 0.f;
        #pragma unroll
        for (int mi = 0; mi < 4; ++mi) {
            #pragma unroll
            for (int r = 0; r < 4; ++r) {
                size_t row = row0 + waveM * 64 + mi * 16 + quad * 4 + r;
                float v = acc[mi][ni][r] + bv;
                if (EPI == 2) v = fmaxf(v, 0.f);
                if constexpr (sizeof(CT) == 2) C[row * (size_t)ldc + col] = (CT)f2u(v);
                else                           C[row * (size_t)ldc + col] = (CT)v;
            }
        }
    }
}

// 8-wide row load -> f32, for f32 or bf16 source
__device__ __forceinline__ void load8_f(const float* p, float* v) {
    float4 a = *(const float4*)p;
    float4 b = *(const float4*)(p + 4);
    v[0] = a.x; v[1] = a.y; v[2] = a.z; v[3] = a.w;
    v[4] = b.x; v[5] = b.y; v[6] = b.z; v[7] = b.w;
}
__device__ __forceinline__ void load8_b(const u16* p, float* v) {
    uint4 a = *(const uint4*)p;
    const u16* ap = (const u16*)&a;
    #pragma unroll
    for (int j = 0; j < 8; ++j) v[j] = u2f(ap[j]);
}

// ---------- aggregation (pre-GEMM): Xa[i] = dinv2[i]*X[i] + sum_e w_e * X[src_e]; Xa bf16 ----------
template <typename XT>
__global__ __launch_bounds__(128)
void k_agg_pre(const XT* __restrict__ X, const int* __restrict__ off,
               const int* __restrict__ csr_src, const float* __restrict__ csr_w,
               const float* __restrict__ dinv2, u16* __restrict__ Xa, int F) {
    const int i = blockIdx.x;
    const int e0 = off[i], e1 = off[i + 1];
    const float d2 = dinv2[i];
    for (int f = threadIdx.x * 8; f < F; f += 128 * 8) {
        float acc[8], hv[8];
        if constexpr (sizeof(XT) == 2) load8_b((const u16*)&X[(size_t)i * F + f], hv);
        else                           load8_f((const float*)&X[(size_t)i * F + f], hv);
        #pragma unroll
        for (int j = 0; j < 8; ++j) acc[j] = d2 * hv[j];
        for (int e = e0; e < e1; ++e) {
            int s = csr_src[e];
            float w = csr_w[e];
            float sv[8];
            if constexpr (sizeof(XT) == 2) load8_b((const u16*)&X[(size_t)s * F + f], sv);
            else                           load8_f((const float*)&X[(size_t)s * F + f], sv);
            #pragma unroll
            for (int j = 0; j < 8; ++j) acc[j] = fmaf(w, sv[j], acc[j]);
        }
        uint4 ov;
        u16* op = (u16*)&ov;
        #pragma unroll
        for (int j = 0; j < 8; ++j) op[j] = f2u(acc[j]);
        *(uint4*)&Xa[(size_t)i * F + f] = ov;
    }
}

// ---------- aggregation (post-GEMM): X[i] = relu(b + dinv2[i]*H[i] + sum_e w_e*H[src_e]) ----------
__global__ __launch_bounds__(128)
void k_agg_post(const u16* __restrict__ H, const int* __restrict__ off,
                const int* __restrict__ csr_src, const float* __restrict__ csr_w,
                const float* __restrict__ dinv2, const float* __restrict__ bias,
                u16* __restrict__ X, int F) {
    const int i = blockIdx.x;
    const int e0 = off[i], e1 = off[i + 1];
    const float d2 = dinv2[i];
    for (int f = threadIdx.x * 8; f < F; f += 128 * 8) {
        float acc[8], hv[8];
        load8_b(&H[(size_t)i * F + f], hv);
        #pragma unroll
        for (int j = 0; j < 8; ++j) acc[j] = fmaf(d2, hv[j], bias[f + j]);
        for (int e = e0; e < e1; ++e) {
            int s = csr_src[e];
            float w = csr_w[e];
            float sv[8];
            load8_b(&H[(size_t)s * F + f], sv);
            #pragma unroll
            for (int j = 0; j < 8; ++j) acc[j] = fmaf(w, sv[j], acc[j]);
        }
        uint4 ov;
        u16* op = (u16*)&ov;
        #pragma unroll
        for (int j = 0; j < 8; ++j) op[j] = f2u(fmaxf(acc[j], 0.f));
        *(uint4*)&X[(size_t)i * F + f] = ov;
    }
}

// ---------------- launch ----------------
extern "C" void kernel_launch(void* const* d_in, const int* in_sizes, int n_in,
                              void* d_out, int out_size, void* d_ws, size_t ws_size,
                              hipStream_t stream) {
    const int N = 16384, E = 65536;
    const float* x   = (const float*)d_in[0];
    const int*   src = (const int*)d_in[1];
    const int*   dst = (const int*)d_in[2];
    const float* ew  = (const float*)d_in[3];
    const float* W[5] = {(const float*)d_in[4], (const float*)d_in[6], (const float*)d_in[8],
                         (const float*)d_in[10], (const float*)d_in[12]};
    const float* b[5] = {(const float*)d_in[5], (const float*)d_in[7], (const float*)d_in[9],
                         (const float*)d_in[11], (const float*)d_in[13]};
    static const int Kd[5] = {512, 1024, 2048, 4096, 2048};   // GEMM K per layer
    static const int Md[5] = {1024, 2048, 4096, 2048, 1000};  // real out cols
    static const int Mp[5] = {1024, 2048, 4096, 2048, 1024};  // padded out cols

    char* ws = (char*)d_ws;
    size_t o = 0;
    auto alloc = [&](size_t bytes) -> void* {
        void* p = ws + o;
        o = (o + bytes + 255) & ~(size_t)255;
        return p;
    };
    // ping-pong activations (bf16): P up to 4096-wide, Q up to 2048-wide  (~234 MiB total ws)
    u16* P = (u16*)alloc((size_t)N * 4096 * 2);   // 128 MiB
    u16* Q = (u16*)alloc((size_t)N * 2048 * 2);   //  64 MiB
    u16* Wt[5];
    for (int i = 0; i < 5; ++i) Wt[i] = (u16*)alloc((size_t)Mp[i] * Kd[i] * 2);  // ~41 MB
    float* deg   = (float*)alloc(N * 4);
    float* dinv  = (float*)alloc(N * 4);
    float* dinv2 = (float*)alloc(N * 4);
    int* cnt     = (int*)alloc(N * 4);
    int* cur     = (int*)alloc(N * 4);
    int* off     = (int*)alloc((N + 1) * 4);
    int* csr_src = (int*)alloc(E * 4);
    float* csr_w = (float*)alloc(E * 4);
    (void)ws_size; (void)in_sizes; (void)n_in; (void)out_size;

    // graph prep
    k_fill_f32<<<N / 256, 256, 0, stream>>>(deg, 1.0f, N);
    k_fill_i32<<<N / 256, 256, 0, stream>>>(cnt, 0, N);
    k_fill_i32<<<N / 256, 256, 0, stream>>>(cur, 0, N);
    k_deg_accum<<<E / 256, 256, 0, stream>>>(dst, ew, deg, E);
    k_finish_deg<<<N / 256, 256, 0, stream>>>(deg, dinv, dinv2, N);
    k_count<<<E / 256, 256, 0, stream>>>(dst, cnt, E);
    k_scan<<<1, 1024, 0, stream>>>(cnt, off, N);
    k_fill_csr<<<E / 256, 256, 0, stream>>>(src, dst, ew, dinv, off, cur, csr_src, csr_w, E);

    // weight transposes f32 -> bf16 (pad Wout cols 1000 -> 1024 with zeros)
    for (int i = 0; i < 5; ++i)
        k_transpose<<<dim3(Mp[i] / 32, Kd[i] / 32), dim3(32, 8), 0, stream>>>(W[i], Wt[i], Kd[i], Md[i]);

    // L1..L3: agg-first (A-hat linear => agg(X W) = (agg X) W), bias+relu in GEMM epilogue
    // grid: x = col tiles (fastest, shares A row-panel), y = row tiles (128)
    k_agg_pre<float><<<N, 128, 0, stream>>>(x, off, csr_src, csr_w, dinv2, Q, 512);
    gemm_bt<2, u16><<<dim3(Mp[0] / 128, 128), 256, 0, stream>>>(Q, Wt[0], b[0], P, Kd[0], Md[0], Md[0]);
    k_agg_pre<u16><<<N, 128, 0, stream>>>(P, off, csr_src, csr_w, dinv2, Q, 1024);
    gemm_bt<2, u16><<<dim3(Mp[1] / 128, 128), 256, 0, stream>>>(Q, Wt[1], b[1], P, Kd[1], Md[1], Md[1]);
    k_agg_pre<u16><<<N, 128, 0, stream>>>(P, off, csr_src, csr_w, dinv2, Q, 2048);
    gemm_bt<2, u16><<<dim3(Mp[2] / 128, 128), 256, 0, stream>>>(Q, Wt[2], b[2], P, Kd[2], Md[2], Md[2]);
    // L4: GEMM-then-agg (agg at 2048 instead of 4096)
    gemm_bt<0, u16><<<dim3(Mp[3] / 128, 128), 256, 0, stream>>>(P, Wt[3], nullptr, Q, Kd[3], Md[3], Md[3]);
    k_agg_post<<<N, 128, 0, stream>>>(Q, off, csr_src, csr_w, dinv2, b[3], P, 2048);
    // L5: output projection -> d_out f32 (Nreal=1000, ldc=1000)
    gemm_bt<1, float><<<dim3(Mp[4] / 128, 128), 256, 0, stream>>>(P, Wt[4], b[4], (float*)d_out, Kd[4], Md[4], 1000);
}